// Round 1
// baseline (113.840 us; speedup 1.0000x reference)
//
#include <hip/hip_runtime.h>
#include <hip/hip_bf16.h>

#define B_ 8
#define W_ 128
#define K_ 2048
#define D_ 256

typedef __attribute__((ext_vector_type(8))) short bf16x8;
typedef __attribute__((ext_vector_type(4))) float f32x4;

// round-to-nearest-even f32 -> bf16 (bit pattern in short)
static __device__ __forceinline__ short f2bf(float f) {
    unsigned int u = __float_as_uint(f);
    unsigned int r = (u + 0x7FFFu + ((u >> 16) & 1u)) >> 16;
    return (short)r;
}

// ---------- k1: w2v[w] = sum_d W_lin[W+w][d] * a[d]  (1 block, 128 threads)
__global__ void k_w2v(const float* __restrict__ W_lin, const float* __restrict__ a,
                      float* __restrict__ w2v) {
    int w = threadIdx.x;
    const float* row = W_lin + (size_t)(W_ + w) * D_;
    float acc = 0.f;
    for (int d = 0; d < D_; ++d) acc += row[d] * a[d];
    w2v[w] = acc;
}

// ---------- k2: u2[b,k] = sum_w x[b,w,k]*w2v[w]; also emit xb = bf16(x)
__global__ void k_u2(const float* __restrict__ x, const float* __restrict__ w2v,
                     float* __restrict__ u2, short* __restrict__ xb) {
    __shared__ float ws[W_];
    int tid = threadIdx.x;
    if (tid < W_) ws[tid] = w2v[tid];
    __syncthreads();
    int bk = blockIdx.x * 256 + tid;          // grid = 64 blocks, covers B*K
    int b = bk >> 11;
    int k = bk & (K_ - 1);
    const float* xp = x + ((size_t)b * W_) * K_ + k;
    short* xbp = xb + ((size_t)b * W_) * K_ + k;
    float acc = 0.f;
    for (int w = 0; w < W_; ++w) {
        float xv = xp[(size_t)w * K_];
        acc += xv * ws[w];
        xbp[(size_t)w * K_] = f2bf(xv);
    }
    u2[bk] = acc;
}

// ---------- k3: Mu2[b] = max_k u2[b,k]   (8 blocks, 256 threads)
__global__ void k_mu2(const float* __restrict__ u2, float* __restrict__ Mu2) {
    __shared__ float red[256];
    int b = blockIdx.x, t = threadIdx.x;
    float m = -1e30f;
    for (int k = t; k < K_; k += 256) m = fmaxf(m, u2[b * K_ + k]);
    red[t] = m;
    __syncthreads();
    for (int s = 128; s > 0; s >>= 1) {
        if (t < s) red[t] = fmaxf(red[t], red[t + s]);
        __syncthreads();
    }
    if (t == 0) Mu2[b] = red[0];
}

// ---------- k4: mb[i] = max_j bias[i,j]   (2048 blocks, 256 threads)
__global__ void k_mb(const float* __restrict__ bias, float* __restrict__ mb) {
    __shared__ float red[256];
    int i = blockIdx.x, t = threadIdx.x;
    const float* row = bias + (size_t)i * K_;
    float m = -1e30f;
    for (int j = t; j < K_; j += 256) m = fmaxf(m, row[j]);
    red[t] = m;
    __syncthreads();
    for (int s = 128; s > 0; s >>= 1) {
        if (t < s) red[t] = fmaxf(red[t], red[t + s]);
        __syncthreads();
    }
    if (t == 0) mb[i] = red[0];
}

// ---------- k5: fused softmax (bound-max, single pass) + P@X^T via MFMA + sigmoid
// grid (32, 8): blockIdx.x = 64-row tile, blockIdx.y = b. 256 threads = 4 waves.
// Each wave: 16 attn rows (one MFMA m-tile), full 128 w cols (8 n-tiles).
// MFMA 16x16x32 bf16. A[m][k]: m=lane&15, k=(lane>>4)*8+t (contiguous 8).
// B[k][n]: n=lane&15, same k. D: col=lane&15, row=(lane>>4)*4+reg.
__global__ __launch_bounds__(256) void k_attn(
        const float* __restrict__ u2, const float* __restrict__ bias,
        const float* __restrict__ Mu2, const float* __restrict__ mb,
        const short* __restrict__ xb, float* __restrict__ out) {
    int b    = blockIdx.y;
    int tid  = threadIdx.x;
    int wid  = tid >> 6;
    int lane = tid & 63;
    int il   = lane & 15;        // m (row) for A, n (col) for B/D
    int kg   = lane >> 4;        // k-group
    int i0   = blockIdx.x * 64 + wid * 16;
    int irow = i0 + il;

    float Mshift = Mu2[b] + mb[irow];
    const float* u2b  = u2 + b * K_;
    const float* brow = bias + (size_t)irow * K_ + kg * 8;
    const short* xbb  = xb + ((size_t)b * W_) * K_;

    f32x4 acc[8];
#pragma unroll
    for (int n = 0; n < 8; ++n) acc[n] = (f32x4){0.f, 0.f, 0.f, 0.f};
    float lp = 0.f;

    for (int j0 = 0; j0 < K_; j0 += 32) {
        int jb = j0 + kg * 8;
        float4 uA = *(const float4*)(u2b + jb);
        float4 uB = *(const float4*)(u2b + jb + 4);
        float4 bA = *(const float4*)(brow + j0);
        float4 bB = *(const float4*)(brow + j0 + 4);

        float p0 = __expf(uA.x + bA.x - Mshift);
        float p1 = __expf(uA.y + bA.y - Mshift);
        float p2 = __expf(uA.z + bA.z - Mshift);
        float p3 = __expf(uA.w + bA.w - Mshift);
        float p4 = __expf(uB.x + bB.x - Mshift);
        float p5 = __expf(uB.y + bB.y - Mshift);
        float p6 = __expf(uB.z + bB.z - Mshift);
        float p7 = __expf(uB.w + bB.w - Mshift);
        lp += ((p0 + p1) + (p2 + p3)) + ((p4 + p5) + (p6 + p7));

        bf16x8 afrag;
        afrag[0] = f2bf(p0); afrag[1] = f2bf(p1);
        afrag[2] = f2bf(p2); afrag[3] = f2bf(p3);
        afrag[4] = f2bf(p4); afrag[5] = f2bf(p5);
        afrag[6] = f2bf(p6); afrag[7] = f2bf(p7);

        const short* xj = xbb + jb;
#pragma unroll
        for (int n = 0; n < 8; ++n) {
            bf16x8 bfrag = *(const bf16x8*)(xj + (size_t)(n * 16 + il) * K_);
            acc[n] = __builtin_amdgcn_mfma_f32_16x16x32_bf16(afrag, bfrag, acc[n], 0, 0, 0);
        }
    }

    // row denominators: rows split over lanes {r, r+16, r+32, r+48}
    lp += __shfl_xor(lp, 16);
    lp += __shfl_xor(lp, 32);
    // lane needs l for D rows kg*4+reg (held replicated at lane (kg*4+reg) mod 16)
    float linv[4];
#pragma unroll
    for (int r = 0; r < 4; ++r) linv[r] = 1.f / __shfl(lp, kg * 4 + r);

#pragma unroll
    for (int n = 0; n < 8; ++n) {
        int wcol = n * 16 + il;
        float4 o;
        o.x = 1.f / (1.f + __expf(-acc[n][0] * linv[0]));
        o.y = 1.f / (1.f + __expf(-acc[n][1] * linv[1]));
        o.z = 1.f / (1.f + __expf(-acc[n][2] * linv[2]));
        o.w = 1.f / (1.f + __expf(-acc[n][3] * linv[3]));
        float* op = out + ((size_t)b * W_ + wcol) * K_ + i0 + kg * 4;
        *(float4*)op = o;
    }
}

extern "C" void kernel_launch(void* const* d_in, const int* in_sizes, int n_in,
                              void* d_out, int out_size, void* d_ws, size_t ws_size,
                              hipStream_t stream) {
    const float* x     = (const float*)d_in[0];
    const float* W_lin = (const float*)d_in[1];
    // d_in[2] = b_lin: cancels in softmax, unused
    const float* a     = (const float*)d_in[3];
    const float* bias  = (const float*)d_in[4];
    float* out = (float*)d_out;

    float* w2v = (float*)d_ws;            // 128
    float* u2  = w2v + 128;               // B*K = 16384
    float* Mu2 = u2 + B_ * K_;            // 8
    float* mb  = Mu2 + 8;                 // 2048
    short* xb  = (short*)(mb + K_);       // B*W*K bf16 = 4 MB (offset 74272 B, 16B-aligned)

    k_w2v<<<1, 128, 0, stream>>>(W_lin, a, w2v);
    k_u2 <<<(B_ * K_) / 256, 256, 0, stream>>>(x, w2v, u2, xb);
    k_mu2<<<B_, 256, 0, stream>>>(u2, Mu2);
    k_mb <<<K_, 256, 0, stream>>>(bias, mb);
    k_attn<<<dim3(K_ / 64, B_), 256, 0, stream>>>(u2, bias, Mu2, mb, xb, out);
}

// Round 2
// 100.428 us; speedup vs baseline: 1.1335x; 1.1335x over previous
//
#include <hip/hip_runtime.h>
#include <hip/hip_bf16.h>

#define B_ 8
#define W_ 128
#define K_ 2048
#define D_ 256

typedef __attribute__((ext_vector_type(8))) short bf16x8;
typedef __attribute__((ext_vector_type(4))) float f32x4;

// round-to-nearest-even f32 -> bf16 (bit pattern in short)
static __device__ __forceinline__ short f2bf(float f) {
    unsigned int u = __float_as_uint(f);
    unsigned int r = (u + 0x7FFFu + ((u >> 16) & 1u)) >> 16;
    return (short)r;
}

// ---------- k1: w2v[w] = sum_d W_lin[W+w][d] * a[d]  (128 blocks x 1 wave)
__global__ void k_w2v(const float* __restrict__ W_lin, const float* __restrict__ a,
                      float* __restrict__ w2v) {
    int w = blockIdx.x, l = threadIdx.x;           // l in [0,64)
    float4 rv = ((const float4*)(W_lin + (size_t)(W_ + w) * D_))[l];
    float4 av = ((const float4*)a)[l];
    float acc = rv.x * av.x + rv.y * av.y + rv.z * av.z + rv.w * av.w;
    for (int m = 1; m < 64; m <<= 1) acc += __shfl_xor(acc, m);
    if (l == 0) w2v[w] = acc;
}

// ---------- k2: u2[b,k] = sum_w x[b,w,k]*w2v[w]; also emit xb = bf16(x)
// grid = B*K/32 = 512 blocks, 256 threads: 32 k-cols x 8 w-chunks of 16.
__global__ __launch_bounds__(256) void k_u2(const float* __restrict__ x,
                                            const float* __restrict__ w2v,
                                            float* __restrict__ u2, short* __restrict__ xb) {
    __shared__ float ws[W_];
    __shared__ float red[8][32];
    int tid = threadIdx.x;
    if (tid < W_) ws[tid] = w2v[tid];
    __syncthreads();
    int q = tid & 31;       // k within block
    int c = tid >> 5;       // w chunk
    int bk0 = blockIdx.x * 32;
    int bk = bk0 + q;
    int b = bk >> 11;
    int k = bk & (K_ - 1);
    const float* xp = x + ((size_t)b * W_ + c * 16) * K_ + k;
    short* xbp = xb + ((size_t)b * W_ + c * 16) * K_ + k;
    float acc = 0.f;
#pragma unroll
    for (int w = 0; w < 16; ++w) {
        float xv = xp[(size_t)w * K_];
        acc += xv * ws[c * 16 + w];
        xbp[(size_t)w * K_] = f2bf(xv);
    }
    red[c][q] = acc;
    __syncthreads();
    if (tid < 32) {
        float s = 0.f;
#pragma unroll
        for (int cc = 0; cc < 8; ++cc) s += red[cc][tid];
        u2[bk0 + tid] = s;
    }
}

// ---------- k3: fused prologue (u2-max, bias row-max) + softmax + P@X^T MFMA + sigmoid
// grid (K/16, B) = (128, 8); 256 threads = 4 waves. Block owns 16 attn rows x all 128 w.
// Waves SPLIT THE j (K-reduction) RANGE: wave wid handles j in [wid*512, wid*512+512).
// Final acc/lp reduction through LDS. MFMA 16x16x32 bf16 fragment layout as verified:
//   A: m=lane&15, k=(lane>>4)*8+e ; B: n=lane&15, same k ; D: col=lane&15, row=(lane>>4)*4+r.
__global__ __launch_bounds__(256) void k_attn(
        const float* __restrict__ u2, const float* __restrict__ bias,
        const short* __restrict__ xb, float* __restrict__ out) {
    __shared__ float mb_s[16];
    __shared__ float um_s[4];
    __shared__ float lps[4][16];
    __shared__ f32x4 accs[8][4][64];   // [n][wid][lane] -> lanes contiguous, conflict-free

    int b    = blockIdx.y;
    int tid  = threadIdx.x;
    int wid  = tid >> 6;
    int lane = tid & 63;
    int il   = lane & 15;
    int kg   = lane >> 4;
    int i0   = blockIdx.x * 16;
    int irow = i0 + il;

    const float* u2b = u2 + b * K_;

    // prologue A: umax = max_j u2[b][j]  (2048 vals over 256 threads)
    {
        const float4* up = (const float4*)u2b + tid * 2;
        float4 a0 = up[0], a1 = up[1];
        float um = fmaxf(fmaxf(fmaxf(a0.x, a0.y), fmaxf(a0.z, a0.w)),
                         fmaxf(fmaxf(a1.x, a1.y), fmaxf(a1.z, a1.w)));
        for (int m = 1; m < 64; m <<= 1) um = fmaxf(um, __shfl_xor(um, m));
        if (lane == 0) um_s[wid] = um;
    }
    // prologue B: mb_s[r] = max_j bias[i0+r][j]  (16 threads per row)
    {
        int r = tid >> 4, q = tid & 15;
        const float4* bp = (const float4*)(bias + (size_t)(i0 + r) * K_) + q;
        float m = -1e30f;
#pragma unroll 4
        for (int s = 0; s < 32; ++s) {
            float4 v = bp[s * 16];
            m = fmaxf(m, fmaxf(fmaxf(v.x, v.y), fmaxf(v.z, v.w)));
        }
        for (int mm = 1; mm < 16; mm <<= 1) m = fmaxf(m, __shfl_xor(m, mm));
        if (q == 0) mb_s[r] = m;
    }
    __syncthreads();

    float umax = fmaxf(fmaxf(um_s[0], um_s[1]), fmaxf(um_s[2], um_s[3]));
    float Mshift = umax + mb_s[il];      // >= max_j (u2[j] + bias[irow][j])

    const float* brow = bias + (size_t)irow * K_;
    const short* xbb  = xb + ((size_t)b * W_) * K_;

    f32x4 acc[8];
#pragma unroll
    for (int n = 0; n < 8; ++n) acc[n] = (f32x4){0.f, 0.f, 0.f, 0.f};
    float lp = 0.f;

    int jlo = wid * (K_ / 4);
#pragma unroll 2
    for (int j0 = jlo; j0 < jlo + K_ / 4; j0 += 32) {
        int jb = j0 + kg * 8;
        float4 uA = *(const float4*)(u2b + jb);
        float4 uB = *(const float4*)(u2b + jb + 4);
        float4 bA = *(const float4*)(brow + jb);
        float4 bB = *(const float4*)(brow + jb + 4);

        float p0 = __expf(uA.x + bA.x - Mshift);
        float p1 = __expf(uA.y + bA.y - Mshift);
        float p2 = __expf(uA.z + bA.z - Mshift);
        float p3 = __expf(uA.w + bA.w - Mshift);
        float p4 = __expf(uB.x + bB.x - Mshift);
        float p5 = __expf(uB.y + bB.y - Mshift);
        float p6 = __expf(uB.z + bB.z - Mshift);
        float p7 = __expf(uB.w + bB.w - Mshift);
        lp += ((p0 + p1) + (p2 + p3)) + ((p4 + p5) + (p6 + p7));

        bf16x8 afrag;
        afrag[0] = f2bf(p0); afrag[1] = f2bf(p1);
        afrag[2] = f2bf(p2); afrag[3] = f2bf(p3);
        afrag[4] = f2bf(p4); afrag[5] = f2bf(p5);
        afrag[6] = f2bf(p6); afrag[7] = f2bf(p7);

        const short* xj = xbb + jb;
#pragma unroll
        for (int n = 0; n < 8; ++n) {
            bf16x8 bfrag = *(const bf16x8*)(xj + (size_t)(n * 16 + il) * K_);
            acc[n] = __builtin_amdgcn_mfma_f32_16x16x32_bf16(afrag, bfrag, acc[n], 0, 0, 0);
        }
    }

    // reduce lp (this wave's j-range) to per-row partials
    lp += __shfl_xor(lp, 16);
    lp += __shfl_xor(lp, 32);
    if (lane < 16) lps[wid][lane] = lp;
#pragma unroll
    for (int n = 0; n < 8; ++n) accs[n][wid][lane] = acc[n];
    __syncthreads();

    // cross-wave reduce: wave wid finalizes n-tiles {2wid, 2wid+1}
    float ltot[4];
#pragma unroll
    for (int r = 0; r < 4; ++r) {
        int row = kg * 4 + r;
        ltot[r] = ((lps[0][row] + lps[1][row]) + (lps[2][row] + lps[3][row]));
    }
#pragma unroll
    for (int e = 0; e < 2; ++e) {
        int n = wid * 2 + e;
        f32x4 s = (accs[n][0][lane] + accs[n][1][lane]) + (accs[n][2][lane] + accs[n][3][lane]);
        int wcol = n * 16 + il;
        float4 o;
        o.x = 1.f / (1.f + __expf(-s[0] / ltot[0]));
        o.y = 1.f / (1.f + __expf(-s[1] / ltot[1]));
        o.z = 1.f / (1.f + __expf(-s[2] / ltot[2]));
        o.w = 1.f / (1.f + __expf(-s[3] / ltot[3]));
        float* op = out + ((size_t)b * W_ + wcol) * K_ + i0 + kg * 4;
        *(float4*)op = o;
    }
}

extern "C" void kernel_launch(void* const* d_in, const int* in_sizes, int n_in,
                              void* d_out, int out_size, void* d_ws, size_t ws_size,
                              hipStream_t stream) {
    const float* x     = (const float*)d_in[0];
    const float* W_lin = (const float*)d_in[1];
    // d_in[2] = b_lin: constant along softmax axis -> cancels, unused
    const float* a     = (const float*)d_in[3];
    const float* bias  = (const float*)d_in[4];
    float* out = (float*)d_out;

    float* w2v = (float*)d_ws;            // 128 f32
    float* u2  = w2v + 128;               // B*K = 16384 f32
    short* xb  = (short*)(u2 + B_ * K_);  // B*W*K bf16 = 4 MB (offset 66048 B, 16B-aligned)

    k_w2v<<<128, 64, 0, stream>>>(W_lin, a, w2v);
    k_u2 <<<(B_ * K_) / 32, 256, 0, stream>>>(x, w2v, u2, xb);
    k_attn<<<dim3(K_ / 16, B_), 256, 0, stream>>>(u2, bias, xb, out);
}

// Round 3
// 71.773 us; speedup vs baseline: 1.5861x; 1.3992x over previous
//
#include <hip/hip_runtime.h>
#include <hip/hip_bf16.h>

#define B_ 8
#define W_ 128
#define K_ 2048
#define D_ 256

typedef __attribute__((ext_vector_type(8))) short bf16x8;
typedef __attribute__((ext_vector_type(4))) float f32x4;

// round-to-nearest-even f32 -> bf16 (bit pattern in short)
static __device__ __forceinline__ short f2bf(float f) {
    unsigned int u = __float_as_uint(f);
    unsigned int r = (u + 0x7FFFu + ((u >> 16) & 1u)) >> 16;
    return (short)r;
}

// ---------- k1: w2v[w] = sum_d W_lin[W+w][d] * a[d]  (128 blocks x 1 wave)
__global__ void k_w2v(const float* __restrict__ W_lin, const float* __restrict__ a,
                      float* __restrict__ w2v) {
    int w = blockIdx.x, l = threadIdx.x;           // l in [0,64)
    float4 rv = ((const float4*)(W_lin + (size_t)(W_ + w) * D_))[l];
    float4 av = ((const float4*)a)[l];
    float acc = rv.x * av.x + rv.y * av.y + rv.z * av.z + rv.w * av.w;
    for (int m = 1; m < 64; m <<= 1) acc += __shfl_xor(acc, m);
    if (l == 0) w2v[w] = acc;
}

// ---------- k2: u2[b,k] = sum_w x[b,w,k]*w2v[w]; emit xbt in MFMA-blocked layout
// xbt[b][c=k/8][w][e=k%8]  (so a B-fragment read is 16-lane contiguous)
// grid = B*K/32 = 512 blocks, 256 threads: 32 k-cols x 8 w-chunks of 16.
__global__ __launch_bounds__(256) void k_u2(const float* __restrict__ x,
                                            const float* __restrict__ w2v,
                                            float* __restrict__ u2, short* __restrict__ xbt) {
    __shared__ float ws[W_];
    __shared__ float red[8][32];
    int tid = threadIdx.x;
    if (tid < W_) ws[tid] = w2v[tid];
    __syncthreads();
    int q = tid & 31;       // k within block
    int cw = tid >> 5;      // w chunk
    int bk0 = blockIdx.x * 32;
    int bk = bk0 + q;
    int b = bk >> 11;
    int k = bk & (K_ - 1);
    const float* xp = x + ((size_t)b * W_ + cw * 16) * K_ + k;
    short* xo = xbt + (((size_t)b * 256 + (k >> 3)) * 128 + cw * 16) * 8 + (k & 7);
    float acc = 0.f;
#pragma unroll
    for (int w = 0; w < 16; ++w) {
        float xv = xp[(size_t)w * K_];
        acc += xv * ws[cw * 16 + w];
        xo[w * 8] = f2bf(xv);
    }
    red[cw][q] = acc;
    __syncthreads();
    if (tid < 32) {
        float s = 0.f;
#pragma unroll
        for (int cc = 0; cc < 8; ++cc) s += red[cc][tid];
        u2[bk0 + tid] = s;
    }
}

// ---------- k3: mb[i] = max_j bias[i,j]   (2048 blocks x 1 wave, coalesced float4)
__global__ void k_mb(const float* __restrict__ bias, float* __restrict__ mb) {
    int i = blockIdx.x, l = threadIdx.x;
    const float4* bp = (const float4*)(bias + (size_t)i * K_) + l;
    float m = -1e30f;
#pragma unroll
    for (int s = 0; s < 8; ++s) {
        float4 v = bp[s * 64];
        m = fmaxf(m, fmaxf(fmaxf(v.x, v.y), fmaxf(v.z, v.w)));
    }
    for (int mm = 1; mm < 64; mm <<= 1) m = fmaxf(m, __shfl_xor(m, mm));
    if (l == 0) mb[i] = m;
}

// ---------- k4: fused softmax (bound-max, single pass) + P@X^T MFMA + sigmoid
// grid (K/16, B) = (128, 8); 256 threads = 4 waves. Block owns 16 attn rows x all 128 w.
// Waves split the j (K-reduction) range; final acc/lp reduction through LDS.
// MFMA 16x16x32 bf16: A m=lane&15,k=(lane>>4)*8+e ; B n=lane&15 same k ;
// D col=lane&15, row=(lane>>4)*4+r.
__global__ __launch_bounds__(256) void k_attn(
        const float* __restrict__ u2, const float* __restrict__ bias,
        const float* __restrict__ mb, const short* __restrict__ xbt,
        float* __restrict__ out) {
    __shared__ float um_s[4];
    __shared__ float lps[4][16];
    __shared__ f32x4 accs[8][4][64];   // [n][wid][lane] -> lanes contiguous, conflict-free

    int b    = blockIdx.y;
    int tid  = threadIdx.x;
    int wid  = tid >> 6;
    int lane = tid & 63;
    int il   = lane & 15;
    int kg   = lane >> 4;
    int i0   = blockIdx.x * 16;
    int irow = i0 + il;

    const float* u2b = u2 + b * K_;

    // prologue: umax = max_j u2[b][j]  (2048 vals over 256 threads, hits L2)
    {
        const float4* up = (const float4*)u2b + tid * 2;
        float4 a0 = up[0], a1 = up[1];
        float um = fmaxf(fmaxf(fmaxf(a0.x, a0.y), fmaxf(a0.z, a0.w)),
                         fmaxf(fmaxf(a1.x, a1.y), fmaxf(a1.z, a1.w)));
        for (int m = 1; m < 64; m <<= 1) um = fmaxf(um, __shfl_xor(um, m));
        if (lane == 0) um_s[wid] = um;
    }
    __syncthreads();

    float umax = fmaxf(fmaxf(um_s[0], um_s[1]), fmaxf(um_s[2], um_s[3]));
    float Mshift = umax + mb[irow];      // >= max_j (u2[j] + bias[irow][j])

    int jlo = wid * (K_ / 4);
    const float* brow = bias + (size_t)irow * K_;
    const short* xc   = xbt + (((size_t)b * 256 + (jlo >> 3) + kg) * 128 + il) * 8;

    f32x4 acc[8];
#pragma unroll
    for (int n = 0; n < 8; ++n) acc[n] = (f32x4){0.f, 0.f, 0.f, 0.f};
    float lp = 0.f;

#pragma unroll 2
    for (int j0 = jlo; j0 < jlo + K_ / 4; j0 += 32) {
        int jb = j0 + kg * 8;
        float4 uA = *(const float4*)(u2b + jb);
        float4 uB = *(const float4*)(u2b + jb + 4);
        float4 bA = *(const float4*)(brow + jb);
        float4 bB = *(const float4*)(brow + jb + 4);

        float p0 = __expf(uA.x + bA.x - Mshift);
        float p1 = __expf(uA.y + bA.y - Mshift);
        float p2 = __expf(uA.z + bA.z - Mshift);
        float p3 = __expf(uA.w + bA.w - Mshift);
        float p4 = __expf(uB.x + bB.x - Mshift);
        float p5 = __expf(uB.y + bB.y - Mshift);
        float p6 = __expf(uB.z + bB.z - Mshift);
        float p7 = __expf(uB.w + bB.w - Mshift);
        lp += ((p0 + p1) + (p2 + p3)) + ((p4 + p5) + (p6 + p7));

        bf16x8 afrag;
        afrag[0] = f2bf(p0); afrag[1] = f2bf(p1);
        afrag[2] = f2bf(p2); afrag[3] = f2bf(p3);
        afrag[4] = f2bf(p4); afrag[5] = f2bf(p5);
        afrag[6] = f2bf(p6); afrag[7] = f2bf(p7);

#pragma unroll
        for (int n = 0; n < 8; ++n) {
            bf16x8 bfrag = *(const bf16x8*)(xc + n * 128);
            acc[n] = __builtin_amdgcn_mfma_f32_16x16x32_bf16(afrag, bfrag, acc[n], 0, 0, 0);
        }
        xc += 4096;   // 4 c-chunks (32 j) forward
    }

    // reduce lp (this wave's j-range) to per-row partials
    lp += __shfl_xor(lp, 16);
    lp += __shfl_xor(lp, 32);
    if (lane < 16) lps[wid][lane] = lp;
#pragma unroll
    for (int n = 0; n < 8; ++n) accs[n][wid][lane] = acc[n];
    __syncthreads();

    // cross-wave reduce: wave wid finalizes n-tiles {2wid, 2wid+1}
    float ltot[4];
#pragma unroll
    for (int r = 0; r < 4; ++r) {
        int row = kg * 4 + r;
        ltot[r] = ((lps[0][row] + lps[1][row]) + (lps[2][row] + lps[3][row]));
    }
#pragma unroll
    for (int e = 0; e < 2; ++e) {
        int n = wid * 2 + e;
        f32x4 s = (accs[n][0][lane] + accs[n][1][lane]) + (accs[n][2][lane] + accs[n][3][lane]);
        int wcol = n * 16 + il;
        float4 o;
        o.x = 1.f / (1.f + __expf(-s[0] / ltot[0]));
        o.y = 1.f / (1.f + __expf(-s[1] / ltot[1]));
        o.z = 1.f / (1.f + __expf(-s[2] / ltot[2]));
        o.w = 1.f / (1.f + __expf(-s[3] / ltot[3]));
        float* op = out + ((size_t)b * W_ + wcol) * K_ + i0 + kg * 4;
        *(float4*)op = o;
    }
}

extern "C" void kernel_launch(void* const* d_in, const int* in_sizes, int n_in,
                              void* d_out, int out_size, void* d_ws, size_t ws_size,
                              hipStream_t stream) {
    const float* x     = (const float*)d_in[0];
    const float* W_lin = (const float*)d_in[1];
    // d_in[2] = b_lin: constant along softmax axis -> cancels, unused
    const float* a     = (const float*)d_in[3];
    const float* bias  = (const float*)d_in[4];
    float* out = (float*)d_out;

    float* w2v = (float*)d_ws;            // 128 f32
    float* u2  = w2v + 128;               // B*K = 16384 f32
    float* mb  = u2 + B_ * K_;            // K = 2048 f32
    short* xbt = (short*)(mb + K_);       // B*W*K bf16 blocked = 4 MB (16B-aligned)

    k_w2v<<<128, 64, 0, stream>>>(W_lin, a, w2v);
    k_u2 <<<(B_ * K_) / 32, 256, 0, stream>>>(x, w2v, u2, xbt);
    k_mb <<<K_, 64, 0, stream>>>(bias, mb);
    k_attn<<<dim3(K_ / 16, B_), 256, 0, stream>>>(u2, bias, mb, xbt, out);
}

// Round 4
// 59.566 us; speedup vs baseline: 1.9112x; 1.2049x over previous
//
#include <hip/hip_runtime.h>
#include <hip/hip_bf16.h>

#define B_ 8
#define W_ 128
#define K_ 2048
#define D_ 256

typedef __attribute__((ext_vector_type(8))) short bf16x8;
typedef __attribute__((ext_vector_type(4))) float f32x4;

// round-to-nearest-even f32 -> bf16 (bit pattern in short)
static __device__ __forceinline__ short f2bf(float f) {
    unsigned int u = __float_as_uint(f);
    unsigned int r = (u + 0x7FFFu + ((u >> 16) & 1u)) >> 16;
    return (short)r;
}

// ---------- k1: w2v[w] = sum_d W_lin[W+w][d] * a[d]  (128 blocks x 1 wave)
__global__ void k_w2v(const float* __restrict__ W_lin, const float* __restrict__ a,
                      float* __restrict__ w2v) {
    int w = blockIdx.x, l = threadIdx.x;           // l in [0,64)
    float4 rv = ((const float4*)(W_lin + (size_t)(W_ + w) * D_))[l];
    float4 av = ((const float4*)a)[l];
    float acc = rv.x * av.x + rv.y * av.y + rv.z * av.z + rv.w * av.w;
    for (int m = 1; m < 64; m <<= 1) acc += __shfl_xor(acc, m);
    if (l == 0) w2v[w] = acc;
}

// ---------- k2: u2[b,k] = sum_w x[b,w,k]*w2v[w]; emit xbt in MFMA-blocked layout
// xbt[b][c=k/8][w][e=k%8]  (so a B-fragment read is 16-lane contiguous)
__global__ __launch_bounds__(256) void k_u2(const float* __restrict__ x,
                                            const float* __restrict__ w2v,
                                            float* __restrict__ u2, short* __restrict__ xbt) {
    __shared__ float ws[W_];
    __shared__ float red[8][32];
    int tid = threadIdx.x;
    if (tid < W_) ws[tid] = w2v[tid];
    __syncthreads();
    int q = tid & 31;       // k within block
    int cw = tid >> 5;      // w chunk
    int bk0 = blockIdx.x * 32;
    int bk = bk0 + q;
    int b = bk >> 11;
    int k = bk & (K_ - 1);
    const float* xp = x + ((size_t)b * W_ + cw * 16) * K_ + k;
    short* xo = xbt + (((size_t)b * 256 + (k >> 3)) * 128 + cw * 16) * 8 + (k & 7);
    float acc = 0.f;
#pragma unroll
    for (int w = 0; w < 16; ++w) {
        float xv = xp[(size_t)w * K_];
        acc += xv * ws[cw * 16 + w];
        xo[w * 8] = f2bf(xv);
    }
    red[cw][q] = acc;
    __syncthreads();
    if (tid < 32) {
        float s = 0.f;
#pragma unroll
        for (int cc = 0; cc < 8; ++cc) s += red[cc][tid];
        u2[bk0 + tid] = s;
    }
}

// ---------- k3: mb[i] = max_j bias[i,j]   (2048 blocks x 1 wave, coalesced float4)
__global__ void k_mb(const float* __restrict__ bias, float* __restrict__ mb) {
    int i = blockIdx.x, l = threadIdx.x;
    const float4* bp = (const float4*)(bias + (size_t)i * K_) + l;
    float m = -1e30f;
#pragma unroll
    for (int s = 0; s < 8; ++s) {
        float4 v = bp[s * 64];
        m = fmaxf(m, fmaxf(fmaxf(v.x, v.y), fmaxf(v.z, v.w)));
    }
    for (int mm = 1; mm < 64; mm <<= 1) m = fmaxf(m, __shfl_xor(m, mm));
    if (l == 0) mb[i] = m;
}

// ---------- k4: fused softmax + P@X^T MFMA + sigmoid, software-pipelined.
// grid (K/32, B) = (64, 8); 256 threads = 4 waves.
// wave wid: pair = wid>>1 (16-row half), jh = wid&1 (1024-wide j half).
// Depth-1 prefetch: named sets X/Y hold next iter's 8 xbt frags + 2 bias vecs.
// MFMA 16x16x32 bf16: A m=lane&15,k=(lane>>4)*8+e ; B n=lane&15 same k ;
// D col=lane&15, row=(lane>>4)*4+r.
struct Set {
    float4 bA, bB;
    bf16x8 B0, B1, B2, B3, B4, B5, B6, B7;
};

#define FETCH(S, j0_) do {                                        \
    const short* _xp = XB + (j0_) * 128;                          \
    S.bA = *(const float4*)(brow + (j0_));                        \
    S.bB = *(const float4*)(brow + (j0_) + 4);                    \
    S.B0 = *(const bf16x8*)(_xp);                                 \
    S.B1 = *(const bf16x8*)(_xp + 128);                           \
    S.B2 = *(const bf16x8*)(_xp + 256);                           \
    S.B3 = *(const bf16x8*)(_xp + 384);                           \
    S.B4 = *(const bf16x8*)(_xp + 512);                           \
    S.B5 = *(const bf16x8*)(_xp + 640);                           \
    S.B6 = *(const bf16x8*)(_xp + 768);                           \
    S.B7 = *(const bf16x8*)(_xp + 896);                           \
} while (0)

#define CONSUME(S, j0_) do {                                      \
    int _jb = (j0_) + kg * 8;                                     \
    float4 uA = *(const float4*)(u2b + _jb);                      \
    float4 uB = *(const float4*)(u2b + _jb + 4);                  \
    float p0 = __expf(uA.x + S.bA.x - Mshift);                    \
    float p1 = __expf(uA.y + S.bA.y - Mshift);                    \
    float p2 = __expf(uA.z + S.bA.z - Mshift);                    \
    float p3 = __expf(uA.w + S.bA.w - Mshift);                    \
    float p4 = __expf(uB.x + S.bB.x - Mshift);                    \
    float p5 = __expf(uB.y + S.bB.y - Mshift);                    \
    float p6 = __expf(uB.z + S.bB.z - Mshift);                    \
    float p7 = __expf(uB.w + S.bB.w - Mshift);                    \
    lp += ((p0 + p1) + (p2 + p3)) + ((p4 + p5) + (p6 + p7));      \
    bf16x8 af;                                                    \
    af[0] = f2bf(p0); af[1] = f2bf(p1);                           \
    af[2] = f2bf(p2); af[3] = f2bf(p3);                           \
    af[4] = f2bf(p4); af[5] = f2bf(p5);                           \
    af[6] = f2bf(p6); af[7] = f2bf(p7);                           \
    acc0 = __builtin_amdgcn_mfma_f32_16x16x32_bf16(af, S.B0, acc0, 0, 0, 0); \
    acc1 = __builtin_amdgcn_mfma_f32_16x16x32_bf16(af, S.B1, acc1, 0, 0, 0); \
    acc2 = __builtin_amdgcn_mfma_f32_16x16x32_bf16(af, S.B2, acc2, 0, 0, 0); \
    acc3 = __builtin_amdgcn_mfma_f32_16x16x32_bf16(af, S.B3, acc3, 0, 0, 0); \
    acc4 = __builtin_amdgcn_mfma_f32_16x16x32_bf16(af, S.B4, acc4, 0, 0, 0); \
    acc5 = __builtin_amdgcn_mfma_f32_16x16x32_bf16(af, S.B5, acc5, 0, 0, 0); \
    acc6 = __builtin_amdgcn_mfma_f32_16x16x32_bf16(af, S.B6, acc6, 0, 0, 0); \
    acc7 = __builtin_amdgcn_mfma_f32_16x16x32_bf16(af, S.B7, acc7, 0, 0, 0); \
} while (0)

__global__ __launch_bounds__(256) void k_attn(
        const float* __restrict__ u2, const float* __restrict__ bias,
        const float* __restrict__ mb, const short* __restrict__ xbt,
        float* __restrict__ out) {
    __shared__ float um_s[4];
    __shared__ float lps[2][16];
    __shared__ f32x4 accs[2][8][64];   // [pair][n][lane]

    int b    = blockIdx.y;
    int tid  = threadIdx.x;
    int wid  = tid >> 6;
    int lane = tid & 63;
    int il   = lane & 15;
    int kg   = lane >> 4;
    int pair = wid >> 1;
    int jh   = wid & 1;
    int i0   = blockIdx.x * 32;
    int irow = i0 + pair * 16 + il;

    const float* u2b = u2 + b * K_;

    // prologue: umax = max_j u2[b][j]  (2048 vals over 256 threads, L2-hot)
    {
        const float4* up = (const float4*)u2b + tid * 2;
        float4 a0 = up[0], a1 = up[1];
        float um = fmaxf(fmaxf(fmaxf(a0.x, a0.y), fmaxf(a0.z, a0.w)),
                         fmaxf(fmaxf(a1.x, a1.y), fmaxf(a1.z, a1.w)));
        for (int m = 1; m < 64; m <<= 1) um = fmaxf(um, __shfl_xor(um, m));
        if (lane == 0) um_s[wid] = um;
    }
    __syncthreads();

    float umax = fmaxf(fmaxf(um_s[0], um_s[1]), fmaxf(um_s[2], um_s[3]));
    float Mshift = umax + mb[irow];      // >= max_j (u2[j] + bias[irow][j])

    const float* brow = bias + (size_t)irow * K_ + kg * 8;
    const short* XB   = xbt + (((size_t)b * 256 + kg) * 128 + il) * 8;

    f32x4 acc0{0,0,0,0}, acc1{0,0,0,0}, acc2{0,0,0,0}, acc3{0,0,0,0},
          acc4{0,0,0,0}, acc5{0,0,0,0}, acc6{0,0,0,0}, acc7{0,0,0,0};
    float lp = 0.f;

    int jlo = jh * (K_ / 2);
    int jhi = jlo + K_ / 2;

    Set X, Y;
    FETCH(X, jlo);
    for (int j0 = jlo; j0 < jhi; j0 += 64) {
        FETCH(Y, j0 + 32);
        CONSUME(X, j0);
        if (j0 + 64 < jhi) FETCH(X, j0 + 64);
        CONSUME(Y, j0 + 32);
    }

    // lp: reduce over kg -> per-row totals for this j-half
    lp += __shfl_xor(lp, 16);
    lp += __shfl_xor(lp, 32);

    if (jh) {
        if (lane < 16) lps[pair][lane] = lp;
        accs[pair][0][lane] = acc0; accs[pair][1][lane] = acc1;
        accs[pair][2][lane] = acc2; accs[pair][3][lane] = acc3;
        accs[pair][4][lane] = acc4; accs[pair][5][lane] = acc5;
        accs[pair][6][lane] = acc6; accs[pair][7][lane] = acc7;
    }
    __syncthreads();
    if (!jh) {
        float ltot[4];
#pragma unroll
        for (int r = 0; r < 4; ++r) {
            int row = kg * 4 + r;
            ltot[r] = __shfl(lp, row) + lps[pair][row];
        }
        f32x4 sv[8];
        sv[0] = acc0 + accs[pair][0][lane]; sv[1] = acc1 + accs[pair][1][lane];
        sv[2] = acc2 + accs[pair][2][lane]; sv[3] = acc3 + accs[pair][3][lane];
        sv[4] = acc4 + accs[pair][4][lane]; sv[5] = acc5 + accs[pair][5][lane];
        sv[6] = acc6 + accs[pair][6][lane]; sv[7] = acc7 + accs[pair][7][lane];
#pragma unroll
        for (int n = 0; n < 8; ++n) {
            int wcol = n * 16 + il;
            float4 o;
            o.x = 1.f / (1.f + __expf(-sv[n][0] / ltot[0]));
            o.y = 1.f / (1.f + __expf(-sv[n][1] / ltot[1]));
            o.z = 1.f / (1.f + __expf(-sv[n][2] / ltot[2]));
            o.w = 1.f / (1.f + __expf(-sv[n][3] / ltot[3]));
            float* op = out + ((size_t)b * W_ + wcol) * K_ + i0 + pair * 16 + kg * 4;
            *(float4*)op = o;
        }
    }
}

extern "C" void kernel_launch(void* const* d_in, const int* in_sizes, int n_in,
                              void* d_out, int out_size, void* d_ws, size_t ws_size,
                              hipStream_t stream) {
    const float* x     = (const float*)d_in[0];
    const float* W_lin = (const float*)d_in[1];
    // d_in[2] = b_lin: constant along softmax axis -> cancels, unused
    const float* a     = (const float*)d_in[3];
    const float* bias  = (const float*)d_in[4];
    float* out = (float*)d_out;

    float* w2v = (float*)d_ws;            // 128 f32
    float* u2  = w2v + 128;               // B*K = 16384 f32
    float* mb  = u2 + B_ * K_;            // K = 2048 f32
    short* xbt = (short*)(mb + K_);       // B*W*K bf16 blocked = 4 MB (16B-aligned)

    k_w2v<<<128, 64, 0, stream>>>(W_lin, a, w2v);
    k_u2 <<<(B_ * K_) / 32, 256, 0, stream>>>(x, w2v, u2, xbt);
    k_mb <<<K_, 64, 0, stream>>>(bias, mb);
    k_attn<<<dim3(K_ / 32, B_), 256, 0, stream>>>(u2, bias, mb, xbt, out);
}